// Round 2
// baseline (573.725 us; speedup 1.0000x reference)
//
#include <hip/hip_runtime.h>
#include <stdint.h>

#define B_  16384
#define IN_ 512
#define H_  1024
#define KC_ 1536   // IN_ + H_

typedef unsigned short u16;
typedef __attribute__((ext_vector_type(4))) float f32x4;
typedef __attribute__((ext_vector_type(8))) short s16x8;

// ---------- helpers ----------

__device__ __forceinline__ u16 f2bf(float f) {
  union { float f; uint32_t u; } un; un.f = f;
  uint32_t u = un.u;
  uint32_t r = (u + 0x7FFFu + ((u >> 16) & 1u)) >> 16;   // RNE
  return (u16)r;
}

__device__ __forceinline__ float fast_sigmoid(float x) {
  return 1.f / (1.f + __expf(-x));
}
__device__ __forceinline__ float fast_tanh(float x) {
  return 1.f - 2.f / (1.f + __expf(2.f * x));
}

__device__ __forceinline__ void mfma_bf16(f32x4& d, s16x8 a, s16x8 b) {
  asm("v_mfma_f32_16x16x32_bf16 %0, %1, %2, %0" : "+v"(d) : "v"(a), "v"(b));
}

__device__ __forceinline__ void async_copy16(void* lds, const void* g) {
  __builtin_amdgcn_global_load_lds(
      (const __attribute__((address_space(1))) void*)g,
      (__attribute__((address_space(3))) void*)lds, 16, 0, 0);
}

// ---------- K0: f32 -> bf16 conversion / packing ----------
// comb[b][k]  : k<512 from x, else h_prev            (16384 x 1536 bf16)
// wcat[g][n][k]: g=0..3 -> W_i,W_f,W_o,W_g           (4 x 1024 x 1536 bf16)
// wht2[m][n][k]: m=0 -> W_ht, m=1 -> W_hg            (2 x 1024 x 512 bf16)
__global__ __launch_bounds__(256)
void k0_convert(const float* __restrict__ x, const float* __restrict__ hprev,
                const float* __restrict__ Wi, const float* __restrict__ Wf,
                const float* __restrict__ Wo, const float* __restrict__ Wg,
                const float* __restrict__ Wht, const float* __restrict__ Whg,
                u16* __restrict__ comb, u16* __restrict__ wcat,
                u16* __restrict__ wht2, float* __restrict__ sum_slot)
{
  const int NC_COMB = (B_ * KC_) / 4;          // 6291456
  const int NC_WCAT = (4 * H_ * KC_) / 4;      // 1572864
  const int NC_WHT  = (2 * H_ * IN_) / 4;      // 262144
  const int TOTAL = NC_COMB + NC_WCAT + NC_WHT;
  const int stride = gridDim.x * blockDim.x;

  for (int idx = blockIdx.x * blockDim.x + threadIdx.x; idx < TOTAL; idx += stride) {
    const float* src;
    u16* dst;
    if (idx < NC_COMB) {
      int row = idx / 384, cq = idx % 384;     // 384 = 1536/4 chunks per row
      src = (cq < 128) ? (x + (size_t)row * IN_ + cq * 4)
                       : (hprev + (size_t)row * H_ + (cq - 128) * 4);
      dst = comb + (size_t)idx * 4;
    } else if (idx < NC_COMB + NC_WCAT) {
      int j = idx - NC_COMB;
      int g = j / 393216;                       // 1024*1536/4
      int rem = j % 393216;
      const float* W = (g == 0) ? Wi : (g == 1) ? Wf : (g == 2) ? Wo : Wg;
      src = W + (size_t)rem * 4;
      dst = wcat + (size_t)j * 4;
    } else {
      int j = idx - NC_COMB - NC_WCAT;
      int m = j / 131072;                       // 1024*512/4
      int rem = j % 131072;
      src = (m ? Whg : Wht) + (size_t)rem * 4;
      dst = wht2 + (size_t)j * 4;
    }
    float4 v = *(const float4*)src;
    uint32_t p0 = (uint32_t)f2bf(v.x) | ((uint32_t)f2bf(v.y) << 16);
    uint32_t p1 = (uint32_t)f2bf(v.z) | ((uint32_t)f2bf(v.w) << 16);
    *(uint2*)dst = make_uint2(p0, p1);
  }
  if (blockIdx.x == 0 && threadIdx.x == 0) sum_slot[0] = 0.f;
}

// ---------- K1: gate GEMM + LSTM pointwise ----------
// Block tile: 128 rows x (4 gates x 32 h-cols = 128 eff cols), BK=64.
// B_lds row r: gate g=(r>>4)&3, hcol n=(r>>6)*16 + (r&15).
// 4 waves in 2x2; wave computes 64x64(eff): gates fc=0..3 for 16 h-cols.
__global__ __launch_bounds__(256, 2)
void k1_gates(const u16* __restrict__ comb, const u16* __restrict__ wcat,
              const float* __restrict__ bi, const float* __restrict__ bf_,
              const float* __restrict__ bo, const float* __restrict__ bg,
              const float* __restrict__ c_prev,
              float* __restrict__ c_out, float* __restrict__ h_pre)
{
  __shared__ __attribute__((aligned(128))) char lds[32768];
  char* lds_a = lds;            // 128x64 bf16 = 16KB (content column-chunk-swizzled)
  char* lds_b = lds + 16384;    // 16KB

  const int tid = threadIdx.x;
  const int w = tid >> 6, lane = tid & 63;
  const int lrow = lane & 15, lkg = lane >> 4;
  const int wm = w >> 1, wn = w & 1;
  const int m0 = blockIdx.y * 128;
  const int n0 = blockIdx.x * 32;

  // staging: chunk j = w*256 + t*64 + lane; r=j>>3 row, q=j&7 16B-chunk-in-row
  const u16* agp[4]; const u16* bgp[4];
  char* alp[4]; char* blp[4];
#pragma unroll
  for (int t = 0; t < 4; ++t) {
    int j = w * 256 + t * 64 + lane;
    int r = j >> 3, q = j & 7;
    int qs = q ^ (r & 7);                                     // inverse-swizzled source
    agp[t] = comb + (size_t)(m0 + r) * KC_ + qs * 8;
    alp[t] = lds_a + (w * 256 + t * 64) * 16;
    int g = (r >> 4) & 3, n = ((r >> 6) << 4) + (r & 15);
    bgp[t] = wcat + ((size_t)(g * H_ + n0 + n)) * KC_ + qs * 8;
    blp[t] = lds_b + (w * 256 + t * 64) * 16;
  }

  f32x4 acc[4][4];
#pragma unroll
  for (int i = 0; i < 4; ++i)
#pragma unroll
    for (int j = 0; j < 4; ++j) acc[i][j] = (f32x4){0.f, 0.f, 0.f, 0.f};

  const int sw = (lrow & 7) << 4;   // XOR-swizzle for 128B-stride rows (G4)
  int aoff[4], boff[4];
#pragma unroll
  for (int fm = 0; fm < 4; ++fm) aoff[fm] = (wm * 64 + fm * 16 + lrow) * 128;
#pragma unroll
  for (int fc = 0; fc < 4; ++fc) boff[fc] = (wn * 64 + fc * 16 + lrow) * 128;

  for (int kt = 0; kt < KC_ / 64; ++kt) {
#pragma unroll
    for (int t = 0; t < 4; ++t) {
      async_copy16(alp[t], agp[t] + kt * 64);
      async_copy16(blp[t], bgp[t] + kt * 64);
    }
    __syncthreads();
#pragma unroll
    for (int ks = 0; ks < 2; ++ks) {
      const int koff = (ks * 64 + lkg * 16) ^ sw;
      s16x8 a[4], b[4];
#pragma unroll
      for (int fm = 0; fm < 4; ++fm) a[fm] = *(const s16x8*)(lds_a + aoff[fm] + koff);
#pragma unroll
      for (int fc = 0; fc < 4; ++fc) b[fc] = *(const s16x8*)(lds_b + boff[fc] + koff);
#pragma unroll
      for (int fm = 0; fm < 4; ++fm)
#pragma unroll
        for (int fc = 0; fc < 4; ++fc) mfma_bf16(acc[fm][fc], a[fm], b[fc]);
    }
    __syncthreads();
  }

  // epilogue: i,f,o,g -> c, h_pre
  const int h = n0 + wn * 16 + lrow;
  const float vbi = bi[h], vbf = bf_[h], vbo = bo[h], vbg = bg[h];
#pragma unroll
  for (int fm = 0; fm < 4; ++fm) {
    const int row0 = m0 + wm * 64 + fm * 16 + lkg * 4;
#pragma unroll
    for (int r4 = 0; r4 < 4; ++r4) {
      const size_t off = (size_t)(row0 + r4) * H_ + h;
      float iv = fast_sigmoid(acc[fm][0][r4] + vbi);
      float fv = fast_sigmoid(acc[fm][1][r4] + vbf);
      float ov = fast_sigmoid(acc[fm][2][r4] + vbo);
      float gv = fast_tanh(acc[fm][3][r4] + vbg);
      float c = fv * c_prev[off] + iv * gv;
      c_out[off] = c;
      h_pre[off] = ov * fast_tanh(c);
    }
  }
}

// ---------- K2: attention logits + exp-sum (softmax denom, no max needed) ----------
__global__ __launch_bounds__(256)
void k2_softmax(const float* __restrict__ h_pre, const float* __restrict__ Wa,
                const float* __restrict__ ba, float* __restrict__ e,
                float* __restrict__ sum_slot)
{
  __shared__ float wsum[4];
  const int w = threadIdx.x >> 6, lane = threadIdx.x & 63;
  const int r = blockIdx.x * 4 + w;
  const float4* hp = (const float4*)(h_pre + (size_t)r * H_);
  const float4* wa = (const float4*)Wa;
  float s = 0.f;
#pragma unroll
  for (int j = 0; j < 4; ++j) {
    float4 hv = hp[lane * 4 + j];
    float4 wv = wa[lane * 4 + j];
    s += hv.x * wv.x + hv.y * wv.y + hv.z * wv.z + hv.w * wv.w;
  }
#pragma unroll
  for (int off = 32; off; off >>= 1) s += __shfl_xor(s, off);
  float ev = __expf(s + ba[0]);
  if (lane == 0) { e[r] = ev; wsum[w] = ev; }
  __syncthreads();
  if (threadIdx.x == 0) atomicAdd(sum_slot, wsum[0] + wsum[1] + wsum[2] + wsum[3]);
}

// ---------- K3: highway GEMM + attention scale + merge ----------
// Block tile: 128 rows x (2 mats x 64 h-cols = 128 eff cols), BK=64, K=512.
// B_lds row r: mat=(r>>4)&1, hcol n=(r>>5)*16 + (r&15).
__global__ __launch_bounds__(256, 2)
void k3_highway(const u16* __restrict__ comb, const u16* __restrict__ wht2,
                const float* __restrict__ bht, const float* __restrict__ bhg,
                const float* __restrict__ e, const float* __restrict__ sum_slot,
                float* __restrict__ h_out)   // holds h_pre (f32) on entry
{
  __shared__ __attribute__((aligned(128))) char lds[32768];
  char* lds_a = lds;
  char* lds_b = lds + 16384;

  const int tid = threadIdx.x;
  const int w = tid >> 6, lane = tid & 63;
  const int lrow = lane & 15, lkg = lane >> 4;
  const int wm = w >> 1, wn = w & 1;
  const int m0 = blockIdx.y * 128;
  const int h0 = blockIdx.x * 64;

  const u16* agp[4]; const u16* bgp[4];
  char* alp[4]; char* blp[4];
#pragma unroll
  for (int t = 0; t < 4; ++t) {
    int j = w * 256 + t * 64 + lane;
    int r = j >> 3, q = j & 7;
    int qs = q ^ (r & 7);
    agp[t] = comb + (size_t)(m0 + r) * KC_ + qs * 8;        // x part: cols 0..511
    alp[t] = lds_a + (w * 256 + t * 64) * 16;
    int mat = (r >> 4) & 1, n = ((r >> 5) << 4) + (r & 15);
    bgp[t] = wht2 + ((size_t)(mat * H_ + h0 + n)) * IN_ + qs * 8;
    blp[t] = lds_b + (w * 256 + t * 64) * 16;
  }

  f32x4 acc[4][4];
#pragma unroll
  for (int i = 0; i < 4; ++i)
#pragma unroll
    for (int j = 0; j < 4; ++j) acc[i][j] = (f32x4){0.f, 0.f, 0.f, 0.f};

  const int sw = (lrow & 7) << 4;
  int aoff[4], boff[4];
#pragma unroll
  for (int fm = 0; fm < 4; ++fm) aoff[fm] = (wm * 64 + fm * 16 + lrow) * 128;
#pragma unroll
  for (int fc = 0; fc < 4; ++fc) boff[fc] = (wn * 64 + fc * 16 + lrow) * 128;

  for (int kt = 0; kt < IN_ / 64; ++kt) {
#pragma unroll
    for (int t = 0; t < 4; ++t) {
      async_copy16(alp[t], agp[t] + kt * 64);
      async_copy16(blp[t], bgp[t] + kt * 64);
    }
    __syncthreads();
#pragma unroll
    for (int ks = 0; ks < 2; ++ks) {
      const int koff = (ks * 64 + lkg * 16) ^ sw;
      s16x8 a[4], b[4];
#pragma unroll
      for (int fm = 0; fm < 4; ++fm) a[fm] = *(const s16x8*)(lds_a + aoff[fm] + koff);
#pragma unroll
      for (int fc = 0; fc < 4; ++fc) b[fc] = *(const s16x8*)(lds_b + boff[fc] + koff);
#pragma unroll
      for (int fm = 0; fm < 4; ++fm)
#pragma unroll
        for (int fc = 0; fc < 4; ++fc) mfma_bf16(acc[fm][fc], a[fm], b[fc]);
    }
    __syncthreads();
  }

  const float invs = 1.f / sum_slot[0];
  const int hA = h0 + wn * 32 + lrow;
  const float vbht0 = bht[hA], vbht1 = bht[hA + 16];
  const float vbhg0 = bhg[hA], vbhg1 = bhg[hA + 16];
#pragma unroll
  for (int fm = 0; fm < 4; ++fm) {
    const int row0 = m0 + wm * 64 + fm * 16 + lkg * 4;
#pragma unroll
    for (int r4 = 0; r4 < 4; ++r4) {
      const int row = row0 + r4;
      const float escale = e[row] * invs;
#pragma unroll
      for (int hc = 0; hc < 2; ++hc) {
        const int h = hA + hc * 16;
        const size_t off = (size_t)row * H_ + h;
        float tv = acc[fm][2 * hc][r4] + (hc ? vbht1 : vbht0);
        float gv = fast_sigmoid(acc[fm][2 * hc + 1][r4] + (hc ? vbhg1 : vbhg0));
        float ha = h_out[off] * escale;          // h_pre * attn
        h_out[off] = gv * tv + (1.f - gv) * ha;
      }
    }
  }
}

// ---------- launch ----------
extern "C" void kernel_launch(void* const* d_in, const int* in_sizes, int n_in,
                              void* d_out, int out_size, void* d_ws, size_t ws_size,
                              hipStream_t stream) {
  const float* x      = (const float*)d_in[0];
  const float* h_prev = (const float*)d_in[1];
  const float* c_prev = (const float*)d_in[2];
  const float* Wi  = (const float*)d_in[3];
  const float* bi  = (const float*)d_in[4];
  const float* Wf  = (const float*)d_in[5];
  const float* bf_ = (const float*)d_in[6];
  const float* Wo  = (const float*)d_in[7];
  const float* bo  = (const float*)d_in[8];
  const float* Wg  = (const float*)d_in[9];
  const float* bg  = (const float*)d_in[10];
  const float* Wa  = (const float*)d_in[11];
  const float* ba  = (const float*)d_in[12];
  const float* Wht = (const float*)d_in[13];
  const float* bht = (const float*)d_in[14];
  const float* Whg = (const float*)d_in[15];
  const float* bhg = (const float*)d_in[16];

  char* ws = (char*)d_ws;
  float* sum_slot = (float*)(ws + 0);
  float* e        = (float*)(ws + 256);
  u16* comb = (u16*)(ws + 65792);       // 16384*1536*2 = 50331648 B
  u16* wcat = (u16*)(ws + 50397440);    // 4*1024*1536*2 = 12582912 B
  u16* wht2 = (u16*)(ws + 62980352);    // 2*1024*512*2 = 2097152 B -> end 65077504

  float* h_out = (float*)d_out;                      // also h_pre scratch (f32)
  float* c_out = (float*)d_out + (size_t)B_ * H_;

  hipLaunchKernelGGL(k0_convert, dim3(2048), dim3(256), 0, stream,
                     x, h_prev, Wi, Wf, Wo, Wg, Wht, Whg, comb, wcat, wht2, sum_slot);
  hipLaunchKernelGGL(k1_gates, dim3(H_ / 32, B_ / 128), dim3(256), 0, stream,
                     comb, wcat, bi, bf_, bo, bg, c_prev, c_out, h_out);
  hipLaunchKernelGGL(k2_softmax, dim3(B_ / 4), dim3(256), 0, stream,
                     h_out, Wa, ba, e, sum_slot);
  hipLaunchKernelGGL(k3_highway, dim3(H_ / 64, B_ / 128), dim3(256), 0, stream,
                     comb, wht2, bht, bhg, e, sum_slot, h_out);
}

// Round 3
// 532.084 us; speedup vs baseline: 1.0783x; 1.0783x over previous
//
#include <hip/hip_runtime.h>
#include <stdint.h>

#define B_  16384
#define IN_ 512
#define H_  1024
#define KC_ 1536   // IN_ + H_

typedef unsigned short u16;
typedef __attribute__((ext_vector_type(4))) float f32x4;
typedef __attribute__((ext_vector_type(8))) short s16x8;

// ---------- helpers ----------

__device__ __forceinline__ u16 f2bf(float f) {
  union { float f; uint32_t u; } un; un.f = f;
  uint32_t u = un.u;
  uint32_t r = (u + 0x7FFFu + ((u >> 16) & 1u)) >> 16;   // RNE
  return (u16)r;
}

__device__ __forceinline__ float fast_sigmoid(float x) {
  return 1.f / (1.f + __expf(-x));
}
__device__ __forceinline__ float fast_tanh(float x) {
  return 1.f - 2.f / (1.f + __expf(2.f * x));
}

__device__ __forceinline__ void mfma_bf16(f32x4& d, s16x8 a, s16x8 b) {
  asm volatile("v_mfma_f32_16x16x32_bf16 %0, %1, %2, %0" : "+v"(d) : "v"(a), "v"(b));
}

__device__ __forceinline__ void async_copy16(void* lds, const void* g) {
  __builtin_amdgcn_global_load_lds(
      (const __attribute__((address_space(1))) void*)g,
      (__attribute__((address_space(3))) void*)lds, 16, 0, 0);
}

// ---------- K0: f32 -> bf16 conversion / packing ----------
__global__ __launch_bounds__(256)
void k0_convert(const float* __restrict__ x, const float* __restrict__ hprev,
                const float* __restrict__ Wi, const float* __restrict__ Wf,
                const float* __restrict__ Wo, const float* __restrict__ Wg,
                const float* __restrict__ Wht, const float* __restrict__ Whg,
                u16* __restrict__ comb, u16* __restrict__ wcat,
                u16* __restrict__ wht2)
{
  const int NC_COMB = (B_ * KC_) / 4;          // 6291456
  const int NC_WCAT = (4 * H_ * KC_) / 4;      // 1572864
  const int NC_WHT  = (2 * H_ * IN_) / 4;      // 262144
  const int TOTAL = NC_COMB + NC_WCAT + NC_WHT;
  const int stride = gridDim.x * blockDim.x;

  for (int idx = blockIdx.x * blockDim.x + threadIdx.x; idx < TOTAL; idx += stride) {
    const float* src;
    u16* dst;
    if (idx < NC_COMB) {
      int row = idx / 384, cq = idx % 384;
      src = (cq < 128) ? (x + (size_t)row * IN_ + cq * 4)
                       : (hprev + (size_t)row * H_ + (cq - 128) * 4);
      dst = comb + (size_t)idx * 4;
    } else if (idx < NC_COMB + NC_WCAT) {
      int j = idx - NC_COMB;
      int g = j / 393216;
      int rem = j % 393216;
      const float* W = (g == 0) ? Wi : (g == 1) ? Wf : (g == 2) ? Wo : Wg;
      src = W + (size_t)rem * 4;
      dst = wcat + (size_t)j * 4;
    } else {
      int j = idx - NC_COMB - NC_WCAT;
      int m = j / 131072;
      int rem = j % 131072;
      src = (m ? Whg : Wht) + (size_t)rem * 4;
      dst = wht2 + (size_t)j * 4;
    }
    float4 v = *(const float4*)src;
    uint32_t p0 = (uint32_t)f2bf(v.x) | ((uint32_t)f2bf(v.y) << 16);
    uint32_t p1 = (uint32_t)f2bf(v.z) | ((uint32_t)f2bf(v.w) << 16);
    *(uint2*)dst = make_uint2(p0, p1);
  }
}

// ---------- K1: 256x256-tile 8-phase gate GEMM + LSTM pointwise ----------
// BM=256 rows, BN=256 eff-cols (4 gates x 64 h), BK=64. 8 waves (2M x 4N),
// per-wave 128x64. LDS: 2 bufs x (A 32KB + B 32KB) = 128KB.
// B-tile row r: gate=(r>>4)&3, hcol = n0h + (r>>6)*16 + (r&15).
// Per K-tile: 4 phases (C-quadrants q=0..3), 16 MFMA each. B-frags read at q0,
// held in regs -> B-LDS restaged (tile S+2) at q2/q3; A restaged (S+1) at q0/q1
// of the NEXT parity buffer. Counted vmcnt(4) once per K-tile (G15/T3+T4).
__global__ __launch_bounds__(512, 2)
void k1_gates8ph(const u16* __restrict__ comb, const u16* __restrict__ wcat,
                 const float* __restrict__ bi, const float* __restrict__ bf_,
                 const float* __restrict__ bo, const float* __restrict__ bg,
                 const float* __restrict__ c_prev,
                 float* __restrict__ c_out, float* __restrict__ h_pre)
{
  __shared__ __attribute__((aligned(128))) char lds[131072];

  const int tid = threadIdx.x;
  const int w = tid >> 6, lane = tid & 63;
  const int lrow = lane & 15, lkg = lane >> 4;
  const int wm = w >> 2, wn = w & 3;

  // XCD-aware bijective swizzle (nwg=1024, 1024%8==0)
  int bid = blockIdx.y * gridDim.x + blockIdx.x;
  int swz = (bid & 7) * 128 + (bid >> 3);
  const int bx = swz & 15, by = swz >> 4;
  const int m0 = by * 256, n0h = bx * 64;

  // ---- staging source pointers & LDS dest offsets (half h, load t) ----
  const u16* pA[2][2]; const u16* pB[2][2];
  int ldsA[2][2], ldsB[2][2];
#pragma unroll
  for (int h = 0; h < 2; ++h)
#pragma unroll
    for (int t = 0; t < 2; ++t) {
      int i = w * 128 + t * 64 + lane;     // 0..1023 chunk index in half-tile
      int rh = i >> 3, c = i & 7;
      int cs = c ^ (rh & 7);               // inverse-swizzled source chunk
      int rt = h * 128 + rh;               // row in 256-row tile
      pA[h][t] = comb + (size_t)(m0 + rt) * KC_ + cs * 8;
      int g = (rt >> 4) & 3, hc = n0h + ((rt >> 6) << 4) + (rt & 15);
      pB[h][t] = wcat + ((size_t)(g * H_ + hc)) * KC_ + cs * 8;
      ldsA[h][t] = h * 16384 + (w * 128 + t * 64) * 16;
      ldsB[h][t] = 32768 + h * 16384 + (w * 128 + t * 64) * 16;
    }

  // ---- ds_read offsets ----
  int aoff[8], boff[4], kx[2];
#pragma unroll
  for (int mr = 0; mr < 8; ++mr) aoff[mr] = (wm * 128 + mr * 16 + lrow) * 128;
#pragma unroll
  for (int fc = 0; fc < 4; ++fc) boff[fc] = 32768 + (wn * 64 + fc * 16 + lrow) * 128;
  kx[0] = ((lkg) ^ (lrow & 7)) << 4;
  kx[1] = ((4 + lkg) ^ (lrow & 7)) << 4;

  f32x4 acc[8][4];
#pragma unroll
  for (int i = 0; i < 8; ++i)
#pragma unroll
    for (int j = 0; j < 4; ++j) acc[i][j] = (f32x4){0.f, 0.f, 0.f, 0.f};

  // ---- prologue: A[0],B[0] -> buf0; B[1] -> buf1; wait all but B[1] ----
  {
    char* b0 = lds;
    char* b1 = lds + 65536;
#pragma unroll
    for (int h = 0; h < 2; ++h)
#pragma unroll
      for (int t = 0; t < 2; ++t) async_copy16(b0 + ldsA[h][t], pA[h][t]);
#pragma unroll
    for (int h = 0; h < 2; ++h)
#pragma unroll
      for (int t = 0; t < 2; ++t) async_copy16(b0 + ldsB[h][t], pB[h][t]);
#pragma unroll
    for (int h = 0; h < 2; ++h)
#pragma unroll
      for (int t = 0; t < 2; ++t) async_copy16(b1 + ldsB[h][t], pB[h][t] + 64);
    asm volatile("s_waitcnt vmcnt(4)" ::: "memory");
    __builtin_amdgcn_sched_barrier(0);
    __builtin_amdgcn_s_barrier();
  }

  // ---- main loop over 24 K-tiles ----
  for (int S = 0; S < 24; ++S) {
    const int cur = S & 1;
    char* bufc = lds + cur * 65536;
    char* bufo = lds + (cur ^ 1) * 65536;
    s16x8 bfr[4][2];
#pragma unroll
    for (int q = 0; q < 4; ++q) {
      // ds-reads for this phase
      s16x8 afr[2][2];
#pragma unroll
      for (int j = 0; j < 2; ++j)
#pragma unroll
        for (int kk = 0; kk < 2; ++kk)
          afr[j][kk] = *(const s16x8*)(bufc + aoff[2 * q + j] + kx[kk]);
      if (q == 0) {
#pragma unroll
        for (int fc = 0; fc < 4; ++fc)
#pragma unroll
          for (int kk = 0; kk < 2; ++kk)
            bfr[fc][kk] = *(const s16x8*)(bufc + boff[fc] + kx[kk]);
      }
      // stage one half-tile (issue-early; lands >= 3 phases later)
      if (q == 0 && S < 23) {
        async_copy16(bufo + ldsA[0][0], pA[0][0] + (S + 1) * 64);
        async_copy16(bufo + ldsA[0][1], pA[0][1] + (S + 1) * 64);
      }
      if (q == 1 && S < 23) {
        async_copy16(bufo + ldsA[1][0], pA[1][0] + (S + 1) * 64);
        async_copy16(bufo + ldsA[1][1], pA[1][1] + (S + 1) * 64);
      }
      if (q == 2 && S < 22) {
        async_copy16(bufc + ldsB[0][0], pB[0][0] + (S + 2) * 64);
        async_copy16(bufc + ldsB[0][1], pB[0][1] + (S + 2) * 64);
      }
      if (q == 3 && S < 22) {
        async_copy16(bufc + ldsB[1][0], pB[1][0] + (S + 2) * 64);
        async_copy16(bufc + ldsB[1][1], pB[1][1] + (S + 2) * 64);
      }
      asm volatile("" ::: "memory");
      __builtin_amdgcn_sched_barrier(0);
      __builtin_amdgcn_s_barrier();
      asm volatile("s_waitcnt lgkmcnt(0)" ::: "memory");
      __builtin_amdgcn_sched_barrier(0);
      __builtin_amdgcn_s_setprio(1);
#pragma unroll
      for (int kk = 0; kk < 2; ++kk)
#pragma unroll
        for (int fc = 0; fc < 4; ++fc)
#pragma unroll
          for (int j = 0; j < 2; ++j)
            mfma_bf16(acc[2 * q + j][fc], afr[j][kk], bfr[fc][kk]);
      __builtin_amdgcn_s_setprio(0);
      if (q == 3) {
        if (S < 22) asm volatile("s_waitcnt vmcnt(4)" ::: "memory");
        else        asm volatile("s_waitcnt vmcnt(0)" ::: "memory");
      }
      asm volatile("" ::: "memory");
      __builtin_amdgcn_sched_barrier(0);
      __builtin_amdgcn_s_barrier();
    }
  }

  // ---- epilogue: i,f,o,g -> c, h_pre ----
  const int hcol = n0h + wn * 16 + lrow;
  const float vbi = bi[hcol], vbf = bf_[hcol], vbo = bo[hcol], vbg = bg[hcol];
#pragma unroll
  for (int mr = 0; mr < 8; ++mr) {
    const int row0 = m0 + wm * 128 + mr * 16 + lkg * 4;
#pragma unroll
    for (int r4 = 0; r4 < 4; ++r4) {
      const size_t off = (size_t)(row0 + r4) * H_ + hcol;
      float iv = fast_sigmoid(acc[mr][0][r4] + vbi);
      float fv = fast_sigmoid(acc[mr][1][r4] + vbf);
      float ov = fast_sigmoid(acc[mr][2][r4] + vbo);
      float gv = fast_tanh(acc[mr][3][r4] + vbg);
      float c = fv * c_prev[off] + iv * gv;
      c_out[off] = c;
      h_pre[off] = ov * fast_tanh(c);
    }
  }
}

// ---------- K2a: attention logits + exp, per-block partial sums ----------
__global__ __launch_bounds__(256)
void k2_logits(const float* __restrict__ h_pre, const float* __restrict__ Wa,
               const float* __restrict__ ba, float* __restrict__ e,
               float* __restrict__ partial)
{
  __shared__ float wsum[4];
  const int w = threadIdx.x >> 6, lane = threadIdx.x & 63;
  const int r = blockIdx.x * 4 + w;
  const float4* hp = (const float4*)(h_pre + (size_t)r * H_);
  const float4* wa = (const float4*)Wa;
  float s = 0.f;
#pragma unroll
  for (int j = 0; j < 4; ++j) {
    float4 hv = hp[lane * 4 + j];
    float4 wv = wa[lane * 4 + j];
    s += hv.x * wv.x + hv.y * wv.y + hv.z * wv.z + hv.w * wv.w;
  }
#pragma unroll
  for (int off = 32; off; off >>= 1) s += __shfl_xor(s, off);
  float ev = __expf(s + ba[0]);
  if (lane == 0) { e[r] = ev; wsum[w] = ev; }
  __syncthreads();
  if (threadIdx.x == 0) partial[blockIdx.x] = wsum[0] + wsum[1] + wsum[2] + wsum[3];
}

// ---------- K2b: single-block reduction of 4096 partials ----------
__global__ __launch_bounds__(256)
void k2_reduce(const float* __restrict__ partial, float* __restrict__ sum_slot)
{
  __shared__ float ws4[4];
  float s = 0.f;
  for (int i = threadIdx.x; i < 4096; i += 256) s += partial[i];
#pragma unroll
  for (int off = 32; off; off >>= 1) s += __shfl_xor(s, off);
  if ((threadIdx.x & 63) == 0) ws4[threadIdx.x >> 6] = s;
  __syncthreads();
  if (threadIdx.x == 0) sum_slot[0] = ws4[0] + ws4[1] + ws4[2] + ws4[3];
}

// ---------- K3: highway GEMM + attention scale + merge (128^2 2-phase) ----------
__global__ __launch_bounds__(256, 2)
void k3_highway(const u16* __restrict__ comb, const u16* __restrict__ wht2,
                const float* __restrict__ bht, const float* __restrict__ bhg,
                const float* __restrict__ e, const float* __restrict__ sum_slot,
                float* __restrict__ h_out)   // holds h_pre (f32) on entry
{
  __shared__ __attribute__((aligned(128))) char lds[32768];
  char* lds_a = lds;
  char* lds_b = lds + 16384;

  const int tid = threadIdx.x;
  const int w = tid >> 6, lane = tid & 63;
  const int lrow = lane & 15, lkg = lane >> 4;
  const int wm = w >> 1, wn = w & 1;
  const int m0 = blockIdx.y * 128;
  const int h0 = blockIdx.x * 64;

  const u16* agp[4]; const u16* bgp[4];
  char* alp[4]; char* blp[4];
#pragma unroll
  for (int t = 0; t < 4; ++t) {
    int j = w * 256 + t * 64 + lane;
    int r = j >> 3, q = j & 7;
    int qs = q ^ (r & 7);
    agp[t] = comb + (size_t)(m0 + r) * KC_ + qs * 8;        // x part: cols 0..511
    alp[t] = lds_a + (w * 256 + t * 64) * 16;
    int mat = (r >> 4) & 1, n = ((r >> 5) << 4) + (r & 15);
    bgp[t] = wht2 + ((size_t)(mat * H_ + h0 + n)) * IN_ + qs * 8;
    blp[t] = lds_b + (w * 256 + t * 64) * 16;
  }

  f32x4 acc[4][4];
#pragma unroll
  for (int i = 0; i < 4; ++i)
#pragma unroll
    for (int j = 0; j < 4; ++j) acc[i][j] = (f32x4){0.f, 0.f, 0.f, 0.f};

  const int sw = (lrow & 7) << 4;
  int aoff[4], boff[4];
#pragma unroll
  for (int fm = 0; fm < 4; ++fm) aoff[fm] = (wm * 64 + fm * 16 + lrow) * 128;
#pragma unroll
  for (int fc = 0; fc < 4; ++fc) boff[fc] = (wn * 64 + fc * 16 + lrow) * 128;

  for (int kt = 0; kt < IN_ / 64; ++kt) {
#pragma unroll
    for (int t = 0; t < 4; ++t) {
      async_copy16(alp[t], agp[t] + kt * 64);
      async_copy16(blp[t], bgp[t] + kt * 64);
    }
    __syncthreads();
#pragma unroll
    for (int ks = 0; ks < 2; ++ks) {
      const int koff = (ks * 64 + lkg * 16) ^ sw;
      s16x8 a[4], b[4];
#pragma unroll
      for (int fm = 0; fm < 4; ++fm) a[fm] = *(const s16x8*)(lds_a + aoff[fm] + koff);
#pragma unroll
      for (int fc = 0; fc < 4; ++fc) b[fc] = *(const s16x8*)(lds_b + boff[fc] + koff);
#pragma unroll
      for (int fm = 0; fm < 4; ++fm)
#pragma unroll
        for (int fc = 0; fc < 4; ++fc) mfma_bf16(acc[fm][fc], a[fm], b[fc]);
    }
    __syncthreads();
  }

  const float invs = 1.f / sum_slot[0];
  const int hA = h0 + wn * 32 + lrow;
  const float vbht0 = bht[hA], vbht1 = bht[hA + 16];
  const float vbhg0 = bhg[hA], vbhg1 = bhg[hA + 16];
#pragma unroll
  for (int fm = 0; fm < 4; ++fm) {
    const int row0 = m0 + wm * 64 + fm * 16 + lkg * 4;
#pragma unroll
    for (int r4 = 0; r4 < 4; ++r4) {
      const int row = row0 + r4;
      const float escale = e[row] * invs;
#pragma unroll
      for (int hc = 0; hc < 2; ++hc) {
        const int h = hA + hc * 16;
        const size_t off = (size_t)row * H_ + h;
        float tv = acc[fm][2 * hc][r4] + (hc ? vbht1 : vbht0);
        float gv = fast_sigmoid(acc[fm][2 * hc + 1][r4] + (hc ? vbhg1 : vbhg0));
        float ha = h_out[off] * escale;          // h_pre * attn
        h_out[off] = gv * tv + (1.f - gv) * ha;
      }
    }
  }
}

// ---------- launch ----------
extern "C" void kernel_launch(void* const* d_in, const int* in_sizes, int n_in,
                              void* d_out, int out_size, void* d_ws, size_t ws_size,
                              hipStream_t stream) {
  const float* x      = (const float*)d_in[0];
  const float* h_prev = (const float*)d_in[1];
  const float* c_prev = (const float*)d_in[2];
  const float* Wi  = (const float*)d_in[3];
  const float* bi  = (const float*)d_in[4];
  const float* Wf  = (const float*)d_in[5];
  const float* bf_ = (const float*)d_in[6];
  const float* Wo  = (const float*)d_in[7];
  const float* bo  = (const float*)d_in[8];
  const float* Wg  = (const float*)d_in[9];
  const float* bg  = (const float*)d_in[10];
  const float* Wa  = (const float*)d_in[11];
  const float* ba  = (const float*)d_in[12];
  const float* Wht = (const float*)d_in[13];
  const float* bht = (const float*)d_in[14];
  const float* Whg = (const float*)d_in[15];
  const float* bhg = (const float*)d_in[16];

  char* ws = (char*)d_ws;
  float* sum_slot = (float*)(ws + 0);
  float* e        = (float*)(ws + 256);
  u16* comb = (u16*)(ws + 65792);       // 16384*1536*2 = 50331648 B
  u16* wcat = (u16*)(ws + 50397440);    // 4*1024*1536*2 = 12582912 B
  u16* wht2 = (u16*)(ws + 62980352);    // 2*1024*512*2 = 2097152 B -> end 65077504
  float* partial = (float*)(ws + 65077504);   // 4096 floats -> end 65093888

  float* h_out = (float*)d_out;                      // also h_pre scratch (f32)
  float* c_out = (float*)d_out + (size_t)B_ * H_;

  hipLaunchKernelGGL(k0_convert, dim3(2048), dim3(256), 0, stream,
                     x, h_prev, Wi, Wf, Wo, Wg, Wht, Whg, comb, wcat, wht2);
  hipLaunchKernelGGL(k1_gates8ph, dim3(16, 64), dim3(512), 0, stream,
                     comb, wcat, bi, bf_, bo, bg, c_prev, c_out, h_out);
  hipLaunchKernelGGL(k2_logits, dim3(B_ / 4), dim3(256), 0, stream,
                     h_out, Wa, ba, e, partial);
  hipLaunchKernelGGL(k2_reduce, dim3(1), dim3(256), 0, stream,
                     partial, sum_slot);
  hipLaunchKernelGGL(k3_highway, dim3(H_ / 64, B_ / 128), dim3(256), 0, stream,
                     comb, wht2, bht, bhg, e, sum_slot, h_out);
}